// Round 10
// baseline (38.250 us; speedup 1.0000x reference)
//
#include <hip/hip_runtime.h>

// TweetRep: x (8,6,32,32,30) int32, embeddings (50000,64) f32 -> out (8,384,32,32) f32.
// Round-10: r9 structure (8 pixels/wave, single fp16 gather, rows in 120 VGPRs,
// chunked online softmax) + NON-TEMPORAL hints on all streaming traffic
// (x loads, out stores, cvt's f32 reads). Model: dur is bound by L2-miss fill
// of the random table gather (~3.5 TB/s TCC fill, observed r2-r7); streaming
// data (~18.5MB x+out + 12.8MB cvt reads) evicts table lines from the 4MiB
// per-XCD L2 (table 6.4MB already > capacity). nt = evict-first, still
// cached & write-combined on CDNA (not a bypass) -> protects table residency.

#define LTOK 30
#define NPIX (8 * 6 * 32 * 32)   // 49152
#define L2E  1.4426950408889634f
#define TABROWS 50000
#define TABN (TABROWS * 64)      // 3.2M floats

typedef _Float16 h2 __attribute__((ext_vector_type(2)));
typedef int   v4i __attribute__((ext_vector_type(4)));
typedef int   v2i __attribute__((ext_vector_type(2)));
typedef float v4f __attribute__((ext_vector_type(4)));

template <int CTRL>
__device__ __forceinline__ float dppadd(float v) {
    int t = __builtin_amdgcn_update_dpp(0, __float_as_int(v), CTRL, 0xF, 0xF, true);
    return v + __int_as_float(t);
}

// sum across the 8-lane group: xor1, xor2 (quad sums), then half-row mirror
__device__ __forceinline__ float group8_sum(float p) {
    p = dppadd<0xB1>(p);    // quad_perm {1,0,3,2}
    p = dppadd<0x4E>(p);    // quad_perm {2,3,0,1}
    p = dppadd<0x141>(p);   // row_half_mirror
    return p;
}

__device__ __forceinline__ h2 u2h(unsigned int u) {
    return __builtin_bit_cast(h2, u);
}

// ---- prep: f32 table -> fp16 table (RN) in workspace; nt reads, 16B stores
__global__ __launch_bounds__(256) void cvt_kernel(
        const v4f* __restrict__ in, uint4* __restrict__ out)
{
    const int i = blockIdx.x * 256 + threadIdx.x;
    if (i >= TABN / 8) return;                      // 400000 threads
    v4f f0 = __builtin_nontemporal_load(in + 2 * i);
    v4f f1 = __builtin_nontemporal_load(in + 2 * i + 1);
    h2 a0 = { (_Float16)f0.x, (_Float16)f0.y };
    h2 b0 = { (_Float16)f0.z, (_Float16)f0.w };
    h2 a1 = { (_Float16)f1.x, (_Float16)f1.y };
    h2 b1 = { (_Float16)f1.z, (_Float16)f1.w };
    // table writes stay NORMAL (pre-warm L2 with the data the gather wants)
    out[i] = make_uint4(__builtin_bit_cast(unsigned int, a0),
                        __builtin_bit_cast(unsigned int, b0),
                        __builtin_bit_cast(unsigned int, a1),
                        __builtin_bit_cast(unsigned int, b1));
}

// partial dot of this lane's 8 dims against V, then 8-lane group sum
__device__ __forceinline__ float dot8(const uint4 w,
                                      const float4 Va, const float4 Vb) {
    h2 p0 = u2h(w.x), p1 = u2h(w.y), p2 = u2h(w.z), p3 = u2h(w.w);
    float p = (float)p0.x * Va.x;
    p = fmaf((float)p0.y, Va.y, p);
    p = fmaf((float)p1.x, Va.z, p);
    p = fmaf((float)p1.y, Va.w, p);
    p = fmaf((float)p2.x, Vb.x, p);
    p = fmaf((float)p2.y, Vb.y, p);
    p = fmaf((float)p3.x, Vb.z, p);
    p = fmaf((float)p3.y, Vb.w, p);
    return group8_sum(p);
}

__device__ __forceinline__ void vacc(float4& Va, float4& Vb,
                                     const uint4 w, float one) {
    h2 p0 = u2h(w.x), p1 = u2h(w.y), p2 = u2h(w.z), p3 = u2h(w.w);
    Va.x = fmaf((float)p0.x, one, Va.x); Va.y = fmaf((float)p0.y, one, Va.y);
    Va.z = fmaf((float)p1.x, one, Va.z); Va.w = fmaf((float)p1.y, one, Va.w);
    Vb.x = fmaf((float)p2.x, one, Vb.x); Vb.y = fmaf((float)p2.y, one, Vb.y);
    Vb.z = fmaf((float)p3.x, one, Vb.z); Vb.w = fmaf((float)p3.y, one, Vb.w);
}

__device__ __forceinline__ void accum(float4& Aa, float4& Ab,
                                      const uint4 w, float e) {
    h2 p0 = u2h(w.x), p1 = u2h(w.y), p2 = u2h(w.z), p3 = u2h(w.w);
    Aa.x = fmaf((float)p0.x, e, Aa.x); Aa.y = fmaf((float)p0.y, e, Aa.y);
    Aa.z = fmaf((float)p1.x, e, Aa.z); Aa.w = fmaf((float)p1.y, e, Aa.w);
    Ab.x = fmaf((float)p2.x, e, Ab.x); Ab.y = fmaf((float)p2.y, e, Ab.y);
    Ab.z = fmaf((float)p3.x, e, Ab.z); Ab.w = fmaf((float)p3.y, e, Ab.w);
}

// ---- main: single fp16 gather, 8 pixels/wave, rows live in VGPRs ----
__global__ __launch_bounds__(256, 2) void tweetrep_f16(
        const int* __restrict__ x, const uint4* __restrict__ tab,
        float* __restrict__ out)
{
    const int lane8 = threadIdx.x & 7;
    const int pix   = (blockIdx.x << 5) | (threadIdx.x >> 3);  // 32 pixels/block
    const int* xp   = x + pix * LTOK;
    // fp16 row = 64 halves = 8 uint4; this lane's 8 dims = uint4 #lane8
    const uint4* tpl = tab + lane8;

    float one = 1.0f;
    asm volatile("" : "+v"(one));   // keep fmaf((float)h, one, V) as v_fma_mix

    // ---- single gather: all 30 row-slices into registers (120 VGPR) ----
    // x loads are streaming -> nontemporal (don't evict table lines)
    uint4 wg[LTOK];
#pragma unroll
    for (int c = 0; c < 28; c += 4) {
        v4i ii = __builtin_nontemporal_load(
                     reinterpret_cast<const v4i*>(xp + c));
        wg[c]     = tpl[(size_t)ii.x << 3];
        wg[c + 1] = tpl[(size_t)ii.y << 3];
        wg[c + 2] = tpl[(size_t)ii.z << 3];
        wg[c + 3] = tpl[(size_t)ii.w << 3];
    }
    {
        v2i ii = __builtin_nontemporal_load(
                     reinterpret_cast<const v2i*>(xp + 28));
        wg[28] = tpl[(size_t)ii.x << 3];
        wg[29] = tpl[(size_t)ii.y << 3];
    }

    // ---- V = sum of rows (f32 accum via v_fma_mix) ----
    float4 Va = make_float4(0.f, 0.f, 0.f, 0.f);
    float4 Vb = make_float4(0.f, 0.f, 0.f, 0.f);
#pragma unroll
    for (int l = 0; l < LTOK; ++l) vacc(Va, Vb, wg[l], one);

    // ---- chunk-of-4 online softmax, consuming wg from registers ----
    float4 Aa = make_float4(0.f, 0.f, 0.f, 0.f);
    float4 Ab = make_float4(0.f, 0.f, 0.f, 0.f);
    float  den = 0.f;
    float  m   = -3.0e38f;
#pragma unroll
    for (int c = 0; c < 28; c += 4) {
        float p0 = dot8(wg[c],     Va, Vb);
        float p1 = dot8(wg[c + 1], Va, Vb);
        float p2 = dot8(wg[c + 2], Va, Vb);
        float p3 = dot8(wg[c + 3], Va, Vb);

        const float pm = fmaxf(fmaxf(p0, p1), fmaxf(p2, p3));
        const float mn = fmaxf(m, pm);
        const float sc = __builtin_exp2f((m - mn) * L2E);   // 0 on first chunk
        m = mn;
        const float e0 = __builtin_exp2f((p0 - mn) * L2E);
        const float e1 = __builtin_exp2f((p1 - mn) * L2E);
        const float e2 = __builtin_exp2f((p2 - mn) * L2E);
        const float e3 = __builtin_exp2f((p3 - mn) * L2E);
        Aa.x *= sc; Aa.y *= sc; Aa.z *= sc; Aa.w *= sc;
        Ab.x *= sc; Ab.y *= sc; Ab.z *= sc; Ab.w *= sc;
        den  *= sc;
        accum(Aa, Ab, wg[c],     e0);
        accum(Aa, Ab, wg[c + 1], e1);
        accum(Aa, Ab, wg[c + 2], e2);
        accum(Aa, Ab, wg[c + 3], e3);
        den += (e0 + e1) + (e2 + e3);
    }
    {
        float p0 = dot8(wg[28], Va, Vb);
        float p1 = dot8(wg[29], Va, Vb);
        const float pm = fmaxf(p0, p1);
        const float mn = fmaxf(m, pm);
        const float sc = __builtin_exp2f((m - mn) * L2E);
        const float e0 = __builtin_exp2f((p0 - mn) * L2E);
        const float e1 = __builtin_exp2f((p1 - mn) * L2E);
        Aa.x *= sc; Aa.y *= sc; Aa.z *= sc; Aa.w *= sc;
        Ab.x *= sc; Ab.y *= sc; Ab.z *= sc; Ab.w *= sc;
        den  *= sc;
        accum(Aa, Ab, wg[28], e0);
        accum(Aa, Ab, wg[29], e1);
        den += e0 + e1;
    }
    const float inv = __builtin_amdgcn_rcpf(den);

    // ---- out[bt*64 + e][hw], e = 8*lane8 + j ; nt stores (streaming) ----
    const int bt = pix >> 10, hw = pix & 1023;
    float* op = out + (((size_t)(bt * 64 + (lane8 << 3))) << 10) + hw;
    __builtin_nontemporal_store(Aa.x * inv, op);
    __builtin_nontemporal_store(Aa.y * inv, op + 1024);
    __builtin_nontemporal_store(Aa.z * inv, op + 2 * 1024);
    __builtin_nontemporal_store(Aa.w * inv, op + 3 * 1024);
    __builtin_nontemporal_store(Ab.x * inv, op + 4 * 1024);
    __builtin_nontemporal_store(Ab.y * inv, op + 5 * 1024);
    __builtin_nontemporal_store(Ab.z * inv, op + 6 * 1024);
    __builtin_nontemporal_store(Ab.w * inv, op + 7 * 1024);
}

// ---- f32 fallback (round-5 kernel) if workspace is too small ----
__device__ __forceinline__ float group16_sum(float p) {
    p = dppadd<0xB1>(p);
    p = dppadd<0x4E>(p);
    p = dppadd<0x141>(p);
    p = dppadd<0x140>(p);
    return p;
}

__device__ __forceinline__ float dot4_group(const float4& w, const float4& V) {
    float p = w.x * V.x;
    p = fmaf(w.y, V.y, p);
    p = fmaf(w.z, V.z, p);
    p = fmaf(w.w, V.w, p);
    return group16_sum(p);
}

__global__ __launch_bounds__(256) void tweetrep_f32(
        const int* __restrict__ x, const float* __restrict__ emb,
        float* __restrict__ out)
{
    const int lane16 = threadIdx.x & 15;
    const int pix    = (blockIdx.x << 4) | (threadIdx.x >> 4);
    const int eoff   = lane16 << 2;
    const int*   xp   = x + pix * LTOK;
    const float* embl = emb + eoff;

    float4 V = make_float4(0.f, 0.f, 0.f, 0.f);
#pragma unroll
    for (int c = 0; c < 28; c += 4) {
        int4 ii = *reinterpret_cast<const int4*>(xp + c);
        float4 w0 = *reinterpret_cast<const float4*>(embl + ((size_t)ii.x << 6));
        float4 w1 = *reinterpret_cast<const float4*>(embl + ((size_t)ii.y << 6));
        float4 w2 = *reinterpret_cast<const float4*>(embl + ((size_t)ii.z << 6));
        float4 w3 = *reinterpret_cast<const float4*>(embl + ((size_t)ii.w << 6));
        V.x += (w0.x + w1.x) + (w2.x + w3.x);
        V.y += (w0.y + w1.y) + (w2.y + w3.y);
        V.z += (w0.z + w1.z) + (w2.z + w3.z);
        V.w += (w0.w + w1.w) + (w2.w + w3.w);
    }
    {
        int2 ii = *reinterpret_cast<const int2*>(xp + 28);
        float4 w0 = *reinterpret_cast<const float4*>(embl + ((size_t)ii.x << 6));
        float4 w1 = *reinterpret_cast<const float4*>(embl + ((size_t)ii.y << 6));
        V.x += w0.x + w1.x; V.y += w0.y + w1.y;
        V.z += w0.z + w1.z; V.w += w0.w + w1.w;
    }

    float4 acc = make_float4(0.f, 0.f, 0.f, 0.f);
    float  den = 0.f;
    float  m   = -3.0e38f;
#pragma unroll
    for (int c = 0; c < 28; c += 4) {
        int4 ii = *reinterpret_cast<const int4*>(xp + c);
        float4 w0 = *reinterpret_cast<const float4*>(embl + ((size_t)ii.x << 6));
        float4 w1 = *reinterpret_cast<const float4*>(embl + ((size_t)ii.y << 6));
        float4 w2 = *reinterpret_cast<const float4*>(embl + ((size_t)ii.z << 6));
        float4 w3 = *reinterpret_cast<const float4*>(embl + ((size_t)ii.w << 6));
        float p0 = dot4_group(w0, V);
        float p1 = dot4_group(w1, V);
        float p2 = dot4_group(w2, V);
        float p3 = dot4_group(w3, V);
        const float pm = fmaxf(fmaxf(p0, p1), fmaxf(p2, p3));
        const float mn = fmaxf(m, pm);
        const float sc = __builtin_exp2f((m - mn) * L2E);
        m = mn;
        const float e0 = __builtin_exp2f((p0 - mn) * L2E);
        const float e1 = __builtin_exp2f((p1 - mn) * L2E);
        const float e2 = __builtin_exp2f((p2 - mn) * L2E);
        const float e3 = __builtin_exp2f((p3 - mn) * L2E);
        acc.x *= sc; acc.y *= sc; acc.z *= sc; acc.w *= sc; den *= sc;
        acc.x = fmaf(e0, w0.x, acc.x); acc.y = fmaf(e0, w0.y, acc.y);
        acc.z = fmaf(e0, w0.z, acc.z); acc.w = fmaf(e0, w0.w, acc.w);
        acc.x = fmaf(e1, w1.x, acc.x); acc.y = fmaf(e1, w1.y, acc.y);
        acc.z = fmaf(e1, w1.z, acc.z); acc.w = fmaf(e1, w1.w, acc.w);
        acc.x = fmaf(e2, w2.x, acc.x); acc.y = fmaf(e2, w2.y, acc.y);
        acc.z = fmaf(e2, w2.z, acc.z); acc.w = fmaf(e2, w2.w, acc.w);
        acc.x = fmaf(e3, w3.x, acc.x); acc.y = fmaf(e3, w3.y, acc.y);
        acc.z = fmaf(e3, w3.z, acc.z); acc.w = fmaf(e3, w3.w, acc.w);
        den += (e0 + e1) + (e2 + e3);
    }
    {
        int2 ii = *reinterpret_cast<const int2*>(xp + 28);
        float4 w0 = *reinterpret_cast<const float4*>(embl + ((size_t)ii.x << 6));
        float4 w1 = *reinterpret_cast<const float4*>(embl + ((size_t)ii.y << 6));
        float p0 = dot4_group(w0, V);
        float p1 = dot4_group(w1, V);
        const float pm = fmaxf(p0, p1);
        const float mn = fmaxf(m, pm);
        const float sc = __builtin_exp2f((m - mn) * L2E);
        const float e0 = __builtin_exp2f((p0 - mn) * L2E);
        const float e1 = __builtin_exp2f((p1 - mn) * L2E);
        acc.x *= sc; acc.y *= sc; acc.z *= sc; acc.w *= sc; den *= sc;
        acc.x = fmaf(e0, w0.x, acc.x); acc.y = fmaf(e0, w0.y, acc.y);
        acc.z = fmaf(e0, w0.z, acc.z); acc.w = fmaf(e0, w0.w, acc.w);
        acc.x = fmaf(e1, w1.x, acc.x); acc.y = fmaf(e1, w1.y, acc.y);
        acc.z = fmaf(e1, w1.z, acc.z); acc.w = fmaf(e1, w1.w, acc.w);
        den += e0 + e1;
    }
    const float inv = __builtin_amdgcn_rcpf(den);

    const int bt = pix >> 10, hw = pix & 1023;
    float* op = out + (((size_t)(bt * 64 + eoff)) << 10) + hw;
    op[0]    = acc.x * inv;
    op[1024] = acc.y * inv;
    op[2048] = acc.z * inv;
    op[3072] = acc.w * inv;
}

extern "C" void kernel_launch(void* const* d_in, const int* in_sizes, int n_in,
                              void* d_out, int out_size, void* d_ws, size_t ws_size,
                              hipStream_t stream)
{
    const int*   x   = (const int*)d_in[0];
    const float* emb = (const float*)d_in[1];
    float*       out = (float*)d_out;

    const size_t need = (size_t)TABN * 2;   // 6.4 MB fp16 table
    if (ws_size >= need) {
        cvt_kernel<<<(TABN / 8 + 255) / 256, 256, 0, stream>>>(
            (const v4f*)emb, (uint4*)d_ws);
        tweetrep_f16<<<NPIX / 32, 256, 0, stream>>>(
            x, (const uint4*)d_ws, out);
    } else {
        tweetrep_f32<<<NPIX / 16, 256, 0, stream>>>(x, emb, out);
    }
}

// Round 11
// 35.795 us; speedup vs baseline: 1.0686x; 1.0686x over previous
//
#include <hip/hip_runtime.h>

// TweetRep: x (8,6,32,32,30) int32, embeddings (50000,64) f32 -> out (8,384,32,32) f32.
// Round-11: revert to round-9 (best: 34.9us) — 8 pixels/wave, single fp16
// gather, rows in ~120 VGPRs, chunked online softmax. r10's nontemporal
// hints on x/out REGRESSED (+3.3us) -> pollution theory refuted; keep nt
// ONLY on cvt's one-shot f32 reads (protects fp16 table lines in L2).
// Model: bound by random-gather L2-miss fill (~85MB @ ~3.4TB/s TCC path).

#define LTOK 30
#define NPIX (8 * 6 * 32 * 32)   // 49152
#define L2E  1.4426950408889634f
#define TABROWS 50000
#define TABN (TABROWS * 64)      // 3.2M floats

typedef _Float16 h2 __attribute__((ext_vector_type(2)));
typedef float v4f __attribute__((ext_vector_type(4)));

template <int CTRL>
__device__ __forceinline__ float dppadd(float v) {
    int t = __builtin_amdgcn_update_dpp(0, __float_as_int(v), CTRL, 0xF, 0xF, true);
    return v + __int_as_float(t);
}

// sum across the 8-lane group: xor1, xor2 (quad sums), then half-row mirror
__device__ __forceinline__ float group8_sum(float p) {
    p = dppadd<0xB1>(p);    // quad_perm {1,0,3,2}
    p = dppadd<0x4E>(p);    // quad_perm {2,3,0,1}
    p = dppadd<0x141>(p);   // row_half_mirror
    return p;
}

__device__ __forceinline__ h2 u2h(unsigned int u) {
    return __builtin_bit_cast(h2, u);
}

// ---- prep: f32 table -> fp16 table (RN) in workspace; nt on one-shot reads
__global__ __launch_bounds__(256) void cvt_kernel(
        const v4f* __restrict__ in, uint4* __restrict__ out)
{
    const int i = blockIdx.x * 256 + threadIdx.x;
    if (i >= TABN / 8) return;                      // 400000 threads
    v4f f0 = __builtin_nontemporal_load(in + 2 * i);
    v4f f1 = __builtin_nontemporal_load(in + 2 * i + 1);
    h2 a0 = { (_Float16)f0.x, (_Float16)f0.y };
    h2 b0 = { (_Float16)f0.z, (_Float16)f0.w };
    h2 a1 = { (_Float16)f1.x, (_Float16)f1.y };
    h2 b1 = { (_Float16)f1.z, (_Float16)f1.w };
    out[i] = make_uint4(__builtin_bit_cast(unsigned int, a0),
                        __builtin_bit_cast(unsigned int, b0),
                        __builtin_bit_cast(unsigned int, a1),
                        __builtin_bit_cast(unsigned int, b1));
}

// partial dot of this lane's 8 dims against V, then 8-lane group sum
__device__ __forceinline__ float dot8(const uint4 w,
                                      const float4 Va, const float4 Vb) {
    h2 p0 = u2h(w.x), p1 = u2h(w.y), p2 = u2h(w.z), p3 = u2h(w.w);
    float p = (float)p0.x * Va.x;
    p = fmaf((float)p0.y, Va.y, p);
    p = fmaf((float)p1.x, Va.z, p);
    p = fmaf((float)p1.y, Va.w, p);
    p = fmaf((float)p2.x, Vb.x, p);
    p = fmaf((float)p2.y, Vb.y, p);
    p = fmaf((float)p3.x, Vb.z, p);
    p = fmaf((float)p3.y, Vb.w, p);
    return group8_sum(p);
}

__device__ __forceinline__ void vacc(float4& Va, float4& Vb,
                                     const uint4 w, float one) {
    h2 p0 = u2h(w.x), p1 = u2h(w.y), p2 = u2h(w.z), p3 = u2h(w.w);
    Va.x = fmaf((float)p0.x, one, Va.x); Va.y = fmaf((float)p0.y, one, Va.y);
    Va.z = fmaf((float)p1.x, one, Va.z); Va.w = fmaf((float)p1.y, one, Va.w);
    Vb.x = fmaf((float)p2.x, one, Vb.x); Vb.y = fmaf((float)p2.y, one, Vb.y);
    Vb.z = fmaf((float)p3.x, one, Vb.z); Vb.w = fmaf((float)p3.y, one, Vb.w);
}

__device__ __forceinline__ void accum(float4& Aa, float4& Ab,
                                      const uint4 w, float e) {
    h2 p0 = u2h(w.x), p1 = u2h(w.y), p2 = u2h(w.z), p3 = u2h(w.w);
    Aa.x = fmaf((float)p0.x, e, Aa.x); Aa.y = fmaf((float)p0.y, e, Aa.y);
    Aa.z = fmaf((float)p1.x, e, Aa.z); Aa.w = fmaf((float)p1.y, e, Aa.w);
    Ab.x = fmaf((float)p2.x, e, Ab.x); Ab.y = fmaf((float)p2.y, e, Ab.y);
    Ab.z = fmaf((float)p3.x, e, Ab.z); Ab.w = fmaf((float)p3.y, e, Ab.w);
}

// ---- main: single fp16 gather, 8 pixels/wave, rows live in VGPRs ----
__global__ __launch_bounds__(256, 2) void tweetrep_f16(
        const int* __restrict__ x, const uint4* __restrict__ tab,
        float* __restrict__ out)
{
    const int lane8 = threadIdx.x & 7;
    const int pix   = (blockIdx.x << 5) | (threadIdx.x >> 3);  // 32 pixels/block
    const int* xp   = x + pix * LTOK;
    // fp16 row = 64 halves = 8 uint4; this lane's 8 dims = uint4 #lane8
    const uint4* tpl = tab + lane8;

    float one = 1.0f;
    asm volatile("" : "+v"(one));   // keep fmaf((float)h, one, V) as v_fma_mix

    // ---- single gather: all 30 row-slices into registers (120 VGPR) ----
    uint4 wg[LTOK];
#pragma unroll
    for (int c = 0; c < 28; c += 4) {
        int4 ii = *reinterpret_cast<const int4*>(xp + c);
        wg[c]     = tpl[(size_t)ii.x << 3];
        wg[c + 1] = tpl[(size_t)ii.y << 3];
        wg[c + 2] = tpl[(size_t)ii.z << 3];
        wg[c + 3] = tpl[(size_t)ii.w << 3];
    }
    {
        int2 ii = *reinterpret_cast<const int2*>(xp + 28);
        wg[28] = tpl[(size_t)ii.x << 3];
        wg[29] = tpl[(size_t)ii.y << 3];
    }

    // ---- V = sum of rows (f32 accum via v_fma_mix) ----
    float4 Va = make_float4(0.f, 0.f, 0.f, 0.f);
    float4 Vb = make_float4(0.f, 0.f, 0.f, 0.f);
#pragma unroll
    for (int l = 0; l < LTOK; ++l) vacc(Va, Vb, wg[l], one);

    // ---- chunk-of-4 online softmax, consuming wg from registers ----
    float4 Aa = make_float4(0.f, 0.f, 0.f, 0.f);
    float4 Ab = make_float4(0.f, 0.f, 0.f, 0.f);
    float  den = 0.f;
    float  m   = -3.0e38f;
#pragma unroll
    for (int c = 0; c < 28; c += 4) {
        float p0 = dot8(wg[c],     Va, Vb);
        float p1 = dot8(wg[c + 1], Va, Vb);
        float p2 = dot8(wg[c + 2], Va, Vb);
        float p3 = dot8(wg[c + 3], Va, Vb);

        const float pm = fmaxf(fmaxf(p0, p1), fmaxf(p2, p3));
        const float mn = fmaxf(m, pm);
        const float sc = __builtin_exp2f((m - mn) * L2E);   // 0 on first chunk
        m = mn;
        const float e0 = __builtin_exp2f((p0 - mn) * L2E);
        const float e1 = __builtin_exp2f((p1 - mn) * L2E);
        const float e2 = __builtin_exp2f((p2 - mn) * L2E);
        const float e3 = __builtin_exp2f((p3 - mn) * L2E);
        Aa.x *= sc; Aa.y *= sc; Aa.z *= sc; Aa.w *= sc;
        Ab.x *= sc; Ab.y *= sc; Ab.z *= sc; Ab.w *= sc;
        den  *= sc;
        accum(Aa, Ab, wg[c],     e0);
        accum(Aa, Ab, wg[c + 1], e1);
        accum(Aa, Ab, wg[c + 2], e2);
        accum(Aa, Ab, wg[c + 3], e3);
        den += (e0 + e1) + (e2 + e3);
    }
    {
        float p0 = dot8(wg[28], Va, Vb);
        float p1 = dot8(wg[29], Va, Vb);
        const float pm = fmaxf(p0, p1);
        const float mn = fmaxf(m, pm);
        const float sc = __builtin_exp2f((m - mn) * L2E);
        const float e0 = __builtin_exp2f((p0 - mn) * L2E);
        const float e1 = __builtin_exp2f((p1 - mn) * L2E);
        Aa.x *= sc; Aa.y *= sc; Aa.z *= sc; Aa.w *= sc;
        Ab.x *= sc; Ab.y *= sc; Ab.z *= sc; Ab.w *= sc;
        den  *= sc;
        accum(Aa, Ab, wg[28], e0);
        accum(Aa, Ab, wg[29], e1);
        den += e0 + e1;
    }
    const float inv = __builtin_amdgcn_rcpf(den);

    // ---- out[bt*64 + e][hw], e = 8*lane8 + j ----
    const int bt = pix >> 10, hw = pix & 1023;
    float* op = out + (((size_t)(bt * 64 + (lane8 << 3))) << 10) + hw;
    op[0]        = Aa.x * inv;
    op[1024]     = Aa.y * inv;
    op[2 * 1024] = Aa.z * inv;
    op[3 * 1024] = Aa.w * inv;
    op[4 * 1024] = Ab.x * inv;
    op[5 * 1024] = Ab.y * inv;
    op[6 * 1024] = Ab.z * inv;
    op[7 * 1024] = Ab.w * inv;
}

// ---- f32 fallback (round-5 kernel) if workspace is too small ----
__device__ __forceinline__ float group16_sum(float p) {
    p = dppadd<0xB1>(p);
    p = dppadd<0x4E>(p);
    p = dppadd<0x141>(p);
    p = dppadd<0x140>(p);
    return p;
}

__device__ __forceinline__ float dot4_group(const float4& w, const float4& V) {
    float p = w.x * V.x;
    p = fmaf(w.y, V.y, p);
    p = fmaf(w.z, V.z, p);
    p = fmaf(w.w, V.w, p);
    return group16_sum(p);
}

__global__ __launch_bounds__(256) void tweetrep_f32(
        const int* __restrict__ x, const float* __restrict__ emb,
        float* __restrict__ out)
{
    const int lane16 = threadIdx.x & 15;
    const int pix    = (blockIdx.x << 4) | (threadIdx.x >> 4);
    const int eoff   = lane16 << 2;
    const int*   xp   = x + pix * LTOK;
    const float* embl = emb + eoff;

    float4 V = make_float4(0.f, 0.f, 0.f, 0.f);
#pragma unroll
    for (int c = 0; c < 28; c += 4) {
        int4 ii = *reinterpret_cast<const int4*>(xp + c);
        float4 w0 = *reinterpret_cast<const float4*>(embl + ((size_t)ii.x << 6));
        float4 w1 = *reinterpret_cast<const float4*>(embl + ((size_t)ii.y << 6));
        float4 w2 = *reinterpret_cast<const float4*>(embl + ((size_t)ii.z << 6));
        float4 w3 = *reinterpret_cast<const float4*>(embl + ((size_t)ii.w << 6));
        V.x += (w0.x + w1.x) + (w2.x + w3.x);
        V.y += (w0.y + w1.y) + (w2.y + w3.y);
        V.z += (w0.z + w1.z) + (w2.z + w3.z);
        V.w += (w0.w + w1.w) + (w2.w + w3.w);
    }
    {
        int2 ii = *reinterpret_cast<const int2*>(xp + 28);
        float4 w0 = *reinterpret_cast<const float4*>(embl + ((size_t)ii.x << 6));
        float4 w1 = *reinterpret_cast<const float4*>(embl + ((size_t)ii.y << 6));
        V.x += w0.x + w1.x; V.y += w0.y + w1.y;
        V.z += w0.z + w1.z; V.w += w0.w + w1.w;
    }

    float4 acc = make_float4(0.f, 0.f, 0.f, 0.f);
    float  den = 0.f;
    float  m   = -3.0e38f;
#pragma unroll
    for (int c = 0; c < 28; c += 4) {
        int4 ii = *reinterpret_cast<const int4*>(xp + c);
        float4 w0 = *reinterpret_cast<const float4*>(embl + ((size_t)ii.x << 6));
        float4 w1 = *reinterpret_cast<const float4*>(embl + ((size_t)ii.y << 6));
        float4 w2 = *reinterpret_cast<const float4*>(embl + ((size_t)ii.z << 6));
        float4 w3 = *reinterpret_cast<const float4*>(embl + ((size_t)ii.w << 6));
        float p0 = dot4_group(w0, V);
        float p1 = dot4_group(w1, V);
        float p2 = dot4_group(w2, V);
        float p3 = dot4_group(w3, V);
        const float pm = fmaxf(fmaxf(p0, p1), fmaxf(p2, p3));
        const float mn = fmaxf(m, pm);
        const float sc = __builtin_exp2f((m - mn) * L2E);
        m = mn;
        const float e0 = __builtin_exp2f((p0 - mn) * L2E);
        const float e1 = __builtin_exp2f((p1 - mn) * L2E);
        const float e2 = __builtin_exp2f((p2 - mn) * L2E);
        const float e3 = __builtin_exp2f((p3 - mn) * L2E);
        acc.x *= sc; acc.y *= sc; acc.z *= sc; acc.w *= sc; den *= sc;
        acc.x = fmaf(e0, w0.x, acc.x); acc.y = fmaf(e0, w0.y, acc.y);
        acc.z = fmaf(e0, w0.z, acc.z); acc.w = fmaf(e0, w0.w, acc.w);
        acc.x = fmaf(e1, w1.x, acc.x); acc.y = fmaf(e1, w1.y, acc.y);
        acc.z = fmaf(e1, w1.z, acc.z); acc.w = fmaf(e1, w1.w, acc.w);
        acc.x = fmaf(e2, w2.x, acc.x); acc.y = fmaf(e2, w2.y, acc.y);
        acc.z = fmaf(e2, w2.z, acc.z); acc.w = fmaf(e2, w2.w, acc.w);
        acc.x = fmaf(e3, w3.x, acc.x); acc.y = fmaf(e3, w3.y, acc.y);
        acc.z = fmaf(e3, w3.z, acc.z); acc.w = fmaf(e3, w3.w, acc.w);
        den += (e0 + e1) + (e2 + e3);
    }
    {
        int2 ii = *reinterpret_cast<const int2*>(xp + 28);
        float4 w0 = *reinterpret_cast<const float4*>(embl + ((size_t)ii.x << 6));
        float4 w1 = *reinterpret_cast<const float4*>(embl + ((size_t)ii.y << 6));
        float p0 = dot4_group(w0, V);
        float p1 = dot4_group(w1, V);
        const float pm = fmaxf(p0, p1);
        const float mn = fmaxf(m, pm);
        const float sc = __builtin_exp2f((m - mn) * L2E);
        const float e0 = __builtin_exp2f((p0 - mn) * L2E);
        const float e1 = __builtin_exp2f((p1 - mn) * L2E);
        acc.x *= sc; acc.y *= sc; acc.z *= sc; acc.w *= sc; den *= sc;
        acc.x = fmaf(e0, w0.x, acc.x); acc.y = fmaf(e0, w0.y, acc.y);
        acc.z = fmaf(e0, w0.z, acc.z); acc.w = fmaf(e0, w0.w, acc.w);
        acc.x = fmaf(e1, w1.x, acc.x); acc.y = fmaf(e1, w1.y, acc.y);
        acc.z = fmaf(e1, w1.z, acc.z); acc.w = fmaf(e1, w1.w, acc.w);
        den += e0 + e1;
    }
    const float inv = __builtin_amdgcn_rcpf(den);

    const int bt = pix >> 10, hw = pix & 1023;
    float* op = out + (((size_t)(bt * 64 + eoff)) << 10) + hw;
    op[0]    = acc.x * inv;
    op[1024] = acc.y * inv;
    op[2048] = acc.z * inv;
    op[3072] = acc.w * inv;
}

extern "C" void kernel_launch(void* const* d_in, const int* in_sizes, int n_in,
                              void* d_out, int out_size, void* d_ws, size_t ws_size,
                              hipStream_t stream)
{
    const int*   x   = (const int*)d_in[0];
    const float* emb = (const float*)d_in[1];
    float*       out = (float*)d_out;

    const size_t need = (size_t)TABN * 2;   // 6.4 MB fp16 table
    if (ws_size >= need) {
        cvt_kernel<<<(TABN / 8 + 255) / 256, 256, 0, stream>>>(
            (const v4f*)emb, (uint4*)d_ws);
        tweetrep_f16<<<NPIX / 32, 256, 0, stream>>>(
            x, (const uint4*)d_ws, out);
    } else {
        tweetrep_f32<<<NPIX / 16, 256, 0, stream>>>(x, emb, out);
    }
}